// Round 1
// 231.024 us; speedup vs baseline: 1.0945x; 1.0945x over previous
//
#include <hip/hip_runtime.h>
#include <stdint.h>

// QNetSNN: B=16384, HIDDEN=64, T=40. Wave=row, lane=neuron.
// R5: full f32 numerics experiment. The kernel is VALU-issue-bound
// (VALUBusy 56%, HBM 0.08%, zero bank conflicts); the hot sparse loops were
// all v_add_f64 (half rate) plus 2x v_cvt_f64_f32 per spike in the pair
// loop. Reference is f32 JAX, and the f64 version already tolerated spike
// flips (absmax 0.0117) -> f32 accumulation (comparable error to JAX's own
// f32 rounding) should flip at a similar rate while halving VALU cycles.
//
// LDS 32 KB (f32): wsrec [k][n] | fold = Wcin[:,64:]+Wcrec [k][n]
// ws   (f32): wsin32_t [48][64] | wain32_t [8][64] | pair float2 [64][64]
//             pair[k*64+n] = { Warec[n][k], Wcin[n][k] }

__device__ __forceinline__ uint64_t rfl64(uint64_t x) {
    uint32_t lo = (uint32_t)__builtin_amdgcn_readfirstlane((int)(uint32_t)(x & 0xFFFFFFFFull));
    uint32_t hi = (uint32_t)__builtin_amdgcn_readfirstlane((int)(uint32_t)(x >> 32));
    return ((uint64_t)hi << 32) | (uint64_t)lo;
}

__global__ void snn_prep(const float* __restrict__ Wsin, const float* __restrict__ Wain,
                         const float* __restrict__ Warec, const float* __restrict__ Wcin,
                         float* __restrict__ ws) {
    int tid = blockIdx.x * 256 + threadIdx.x;   // 0..11775
    if (tid < 3072) {
        int k = tid >> 6, n = tid & 63;
        ws[tid] = Wsin[n * 48 + k];
    } else if (tid < 3584) {
        int r = tid - 3072; int k = r >> 6, n = r & 63;
        ws[tid] = Wain[n * 8 + k];
    } else if (tid < 11776) {
        int r = tid - 3584; int k = r >> 7; int rem = r & 127; int n = rem >> 1;
        ws[tid] = (rem & 1) ? Wcin[n * 128 + k]    // .y = Wcin1 (cols :64)
                            : Warec[n * 64 + k];   // .x = Warec
    }
}

__launch_bounds__(1024, 4)
__global__ void snn_main(const float* __restrict__ state, const float* __restrict__ action,
                         const float* __restrict__ Wsrec, const float* __restrict__ Wcin,
                         const float* __restrict__ Wcrec, const float* __restrict__ Wro,
                         const float* __restrict__ ws, float* __restrict__ out) {
    __shared__ float lds[8192];  // [0,4096) wsrec [k][n]; [4096,8192) fold [k][n]

    const int tid = threadIdx.x;
    for (int e = tid; e < 8192; e += 1024) {
        int half = e >> 12; int sub = e & 4095; int k = sub >> 6; int n = sub & 63;
        float val;
        if (half == 0) val = Wsrec[n * 64 + k];
        else           val = Wcin[n * 128 + 64 + k] + Wcrec[n * 64 + k];
        lds[e] = val;
    }
    __syncthreads();

    const int lane = tid & 63;
    const int wave = tid >> 6;
    const int row  = blockIdx.x * 16 + wave;

    float cur = 0.f;
    if (lane < 24)      cur = fmaxf( 50.f * state[row * 24 + lane], 0.f);
    else if (lane < 48) cur = fmaxf(-50.f * state[row * 24 + lane - 24], 0.f);
    else if (lane < 52) cur = fmaxf( 50.f * action[row * 4 + lane - 48], 0.f);
    else if (lane < 56) cur = fmaxf(-50.f * action[row * 4 + lane - 52], 0.f);

    // Always-on lanes: after reset venc = 0 + 0.1f*(cur-0) bit-identically every
    // step, so v1>1 <=> spikes every t (incl. t=0). Exact predicate (f32).
    float v1 = 0.f + 0.1f * (cur - 0.f);
    bool alw = (v1 - 1.0f) > 0.f;
    float curv = alw ? 0.f : cur;
    uint64_t AM = rfl64(__ballot(alw));

    const float*  __restrict__ wsin32 = ws;
    const float*  __restrict__ wain32 = ws + 3072;
    const float2* __restrict__ pair   = (const float2*)(ws + 3584);
    const float wro = Wro[lane];

    // Per-lane always-on input sums.
    float Ssin = 0.f, Sain = 0.f;
    {
        uint64_t m = AM & 0x0000FFFFFFFFFFFFull;
        while (m) { int k = __builtin_ctzll(m); m &= m - 1; Ssin += wsin32[(k << 6) + lane]; }
        m = AM >> 48;
        while (m) { int k = __builtin_ctzll(m); m &= m - 1; Sain += wain32[(k << 6) + lane]; }
    }

    float venc = 0.f, v = 0.f, icur = 0.f, vli = 0.f, ili = 0.f, vmax = 0.f;
    uint64_t zmask = 0;  // z_c of previous step

    for (int t = 0; t < 40; ++t) {
        // ---- layer-s threshold: depends only on ENTERING v,icur -> hoist ----
        float vd = v + 0.1f * (icur - v);
        bool zs = (vd - 1.0f) > 0.f;
        float vs_new = zs ? 0.f : vd;
        uint64_t zsm = rfl64(__ballot(zs));

        // ---- pair loop (global float2, L1-resident): Warec + Wcin1 ----
        float pA0 = 0.f, pA1 = 0.f, pC0 = 0.f, pC1 = 0.f;
        {
            uint64_t m = zsm;
            while (m) {
                int k = __builtin_ctzll(m); m &= m - 1;
                float2 w = pair[(k << 6) + lane];
                pA0 += w.x; pC0 += w.y;
                if (m) {
                    k = __builtin_ctzll(m); m &= m - 1;
                    float2 u = pair[(k << 6) + lane];
                    pA1 += u.x; pC1 += u.y;
                }
            }
        }

        // ---- encoder (variable lanes only) ----
        venc = venc + 0.1f * (curv - venc);
        bool esp = (venc - 1.0f) > 0.f;
        venc = esp ? 0.f : venc;
        uint64_t em = rfl64(__ballot(esp));

        // ---- layer-s accumulation ----
        float acc = (icur - 0.2f * icur) + Ssin;
        {
            uint64_t m = em & 0x0000FFFFFFFFFFFFull;   // variable state bits (few)
            while (m) { int k = __builtin_ctzll(m); m &= m - 1; acc += wsin32[(k << 6) + lane]; }
            float a0 = 0.f, a1 = 0.f;
            m = zmask;                                  // recurrent, f32 LDS
            while (m) {
                int k = __builtin_ctzll(m); m &= m - 1; a0 += lds[(k << 6) + lane];
                if (m) { k = __builtin_ctzll(m); m &= m - 1; a1 += lds[(k << 6) + lane]; }
            }
            acc += a0 + a1;
        }
        float icur_s = acc;

        // ---- layer a ----
        vd = vs_new + 0.1f * (icur_s - vs_new);
        bool za = (vd - 1.0f) > 0.f;
        float va_new = za ? 0.f : vd;
        uint64_t zam = rfl64(__ballot(za));

        acc = (icur_s - 0.2f * icur_s) + Sain + (pA0 + pA1);
        {
            uint64_t m = (em >> 48);                    // variable action bits (few)
            while (m) { int k = __builtin_ctzll(m); m &= m - 1; acc += wain32[(k << 6) + lane]; }
        }
        float icur_a = acc;

        // ---- layer c ----
        vd = va_new + 0.1f * (icur_a - va_new);
        bool zc = (vd - 1.0f) > 0.f;
        v = zc ? 0.f : vd;
        zmask = rfl64(__ballot(zc));

        acc = (icur_a - 0.2f * icur_a) + (pC0 + pC1);
        {
            float a0 = 0.f, a1 = 0.f;
            uint64_t m = zam;                           // fold = Wcin2 + Wcrec, f32 LDS
            while (m) {
                int k = __builtin_ctzll(m); m &= m - 1; a0 += lds[4096 + (k << 6) + lane];
                if (m) { k = __builtin_ctzll(m); m &= m - 1; a1 += lds[4096 + (k << 6) + lane]; }
            }
            acc += a0 + a1;
        }
        icur = acc;

        // ---- LI readout (feed-forward only -> f32 reduce) ----
        float p = zc ? wro : 0.f;
        #pragma unroll
        for (int off = 32; off >= 1; off >>= 1) p += __shfl_xor(p, off, 64);
        float vnew = vli + 0.1f * (ili - vli);
        ili = (ili - 0.2f * ili) + p;
        vli = vnew;
        vmax = fmaxf(vmax, vli);
    }

    if (lane == 0) out[row] = vmax;
}

extern "C" void kernel_launch(void* const* d_in, const int* in_sizes, int n_in,
                              void* d_out, int out_size, void* d_ws, size_t ws_size,
                              hipStream_t stream) {
    const float* state  = (const float*)d_in[0];
    const float* action = (const float*)d_in[1];
    const float* Wsin   = (const float*)d_in[2];
    const float* Wsrec  = (const float*)d_in[3];
    const float* Wain   = (const float*)d_in[4];
    const float* Warec  = (const float*)d_in[5];
    const float* Wcin   = (const float*)d_in[6];
    const float* Wcrec  = (const float*)d_in[7];
    const float* Wro    = (const float*)d_in[8];
    float* out = (float*)d_out;
    float* ws  = (float*)d_ws;

    const int B = in_sizes[0] / 24;  // 16384
    snn_prep<<<46, 256, 0, stream>>>(Wsin, Wain, Warec, Wcin, ws);
    snn_main<<<B / 16, 1024, 0, stream>>>(state, action, Wsrec, Wcin, Wcrec, Wro, ws, out);
}

// Round 2
// 222.469 us; speedup vs baseline: 1.1366x; 1.0385x over previous
//
#include <hip/hip_runtime.h>
#include <stdint.h>

// QNetSNN: B=16384, HIDDEN=64, T=40. Wave=row, lane=neuron.
// R6: latency attack. Counters showed VALUBusy 54% with ~7% per-wave issue
// rate -> latency-bound, prime suspect the pair loop's global loads (pair
// 32KB + wsin/wain 14KB > 32KB L1 => L2 latency ~200cy on the hottest
// serial chain). Move pair into LDS (block LDS 32->64KB, still 2 blocks/CU)
// and accumulate it as float2 with packed v_pk_add_f32 (ext_vector +=).
// Arithmetic order preserved -> expect absmax 0.0 again.
//
// LDS 64 KB (f32): [0,4096) wsrec [k][n] | [4096,8192) fold=Wcin2+Wcrec [k][n]
//                  [8192,16384) pair float2 [k][n] = {Warec[n][k], Wcin[n][k]}
// ws   (f32): wsin32_t [48][64] | wain32_t [8][64] | pair (copied to LDS)

typedef float f32x2 __attribute__((ext_vector_type(2)));

__device__ __forceinline__ uint64_t rfl64(uint64_t x) {
    uint32_t lo = (uint32_t)__builtin_amdgcn_readfirstlane((int)(uint32_t)(x & 0xFFFFFFFFull));
    uint32_t hi = (uint32_t)__builtin_amdgcn_readfirstlane((int)(uint32_t)(x >> 32));
    return ((uint64_t)hi << 32) | (uint64_t)lo;
}

__global__ void snn_prep(const float* __restrict__ Wsin, const float* __restrict__ Wain,
                         const float* __restrict__ Warec, const float* __restrict__ Wcin,
                         float* __restrict__ ws) {
    int tid = blockIdx.x * 256 + threadIdx.x;   // 0..11775
    if (tid < 3072) {
        int k = tid >> 6, n = tid & 63;
        ws[tid] = Wsin[n * 48 + k];
    } else if (tid < 3584) {
        int r = tid - 3072; int k = r >> 6, n = r & 63;
        ws[tid] = Wain[n * 8 + k];
    } else if (tid < 11776) {
        int r = tid - 3584; int k = r >> 7; int rem = r & 127; int n = rem >> 1;
        ws[tid] = (rem & 1) ? Wcin[n * 128 + k]    // .y = Wcin1 (cols :64)
                            : Warec[n * 64 + k];   // .x = Warec
    }
}

__launch_bounds__(1024, 4)
__global__ void snn_main(const float* __restrict__ state, const float* __restrict__ action,
                         const float* __restrict__ Wsrec, const float* __restrict__ Wcin,
                         const float* __restrict__ Wcrec, const float* __restrict__ Wro,
                         const float* __restrict__ ws, float* __restrict__ out) {
    __shared__ float lds[16384];  // 64 KB exactly

    const int tid = threadIdx.x;
    for (int e = tid; e < 16384; e += 1024) {
        float val;
        if (e < 4096) {
            int k = e >> 6, n = e & 63;
            val = Wsrec[n * 64 + k];
        } else if (e < 8192) {
            int s = e - 4096; int k = s >> 6, n = s & 63;
            val = Wcin[n * 128 + 64 + k] + Wcrec[n * 64 + k];
        } else {
            val = ws[e - 8192 + 3584];   // pair table, coalesced L2-hit copy
        }
        lds[e] = val;
    }
    __syncthreads();

    const int lane = tid & 63;
    const int wave = tid >> 6;
    const int row  = blockIdx.x * 16 + wave;

    float cur = 0.f;
    if (lane < 24)      cur = fmaxf( 50.f * state[row * 24 + lane], 0.f);
    else if (lane < 48) cur = fmaxf(-50.f * state[row * 24 + lane - 24], 0.f);
    else if (lane < 52) cur = fmaxf( 50.f * action[row * 4 + lane - 48], 0.f);
    else if (lane < 56) cur = fmaxf(-50.f * action[row * 4 + lane - 52], 0.f);

    // Always-on lanes: after reset venc = 0 + 0.1f*(cur-0) bit-identically every
    // step, so v1>1 <=> spikes every t (incl. t=0). Exact predicate (f32).
    float v1 = 0.f + 0.1f * (cur - 0.f);
    bool alw = (v1 - 1.0f) > 0.f;
    float curv = alw ? 0.f : cur;
    uint64_t AM = rfl64(__ballot(alw));

    const float* __restrict__ wsin32 = ws;
    const float* __restrict__ wain32 = ws + 3072;
    const f32x2* pair2 = (const f32x2*)&lds[8192];
    const float wro = Wro[lane];

    // Per-lane always-on input sums.
    float Ssin = 0.f, Sain = 0.f;
    {
        uint64_t m = AM & 0x0000FFFFFFFFFFFFull;
        while (m) { int k = __builtin_ctzll(m); m &= m - 1; Ssin += wsin32[(k << 6) + lane]; }
        m = AM >> 48;
        while (m) { int k = __builtin_ctzll(m); m &= m - 1; Sain += wain32[(k << 6) + lane]; }
    }

    float venc = 0.f, v = 0.f, icur = 0.f, vli = 0.f, ili = 0.f, vmax = 0.f;
    uint64_t zmask = 0;  // z_c of previous step

    for (int t = 0; t < 40; ++t) {
        // ---- layer-s threshold: depends only on ENTERING v,icur -> hoist ----
        float vd = v + 0.1f * (icur - v);
        bool zs = (vd - 1.0f) > 0.f;
        float vs_new = zs ? 0.f : vd;
        uint64_t zsm = rfl64(__ballot(zs));

        // ---- pair loop (LDS float2, packed adds): Warec + Wcin1 ----
        f32x2 accA = {0.f, 0.f}, accB = {0.f, 0.f};
        {
            uint64_t m = zsm;
            while (m) {
                int k = __builtin_ctzll(m); m &= m - 1;
                f32x2 w = pair2[(k << 6) + lane];
                accA += w;                               // v_pk_add_f32
                if (m) {
                    k = __builtin_ctzll(m); m &= m - 1;
                    f32x2 u = pair2[(k << 6) + lane];
                    accB += u;
                }
            }
        }
        f32x2 accP = accA + accB;  // .x = Warec sum, .y = Wcin1 sum (order == R5)

        // ---- encoder (variable lanes only) ----
        venc = venc + 0.1f * (curv - venc);
        bool esp = (venc - 1.0f) > 0.f;
        venc = esp ? 0.f : venc;
        uint64_t em = rfl64(__ballot(esp));

        // ---- layer-s accumulation ----
        float acc = (icur - 0.2f * icur) + Ssin;
        {
            uint64_t m = em & 0x0000FFFFFFFFFFFFull;   // variable state bits (few)
            while (m) { int k = __builtin_ctzll(m); m &= m - 1; acc += wsin32[(k << 6) + lane]; }
            float a0 = 0.f, a1 = 0.f;
            m = zmask;                                  // recurrent, f32 LDS
            while (m) {
                int k = __builtin_ctzll(m); m &= m - 1; a0 += lds[(k << 6) + lane];
                if (m) { k = __builtin_ctzll(m); m &= m - 1; a1 += lds[(k << 6) + lane]; }
            }
            acc += a0 + a1;
        }
        float icur_s = acc;

        // ---- layer a ----
        vd = vs_new + 0.1f * (icur_s - vs_new);
        bool za = (vd - 1.0f) > 0.f;
        float va_new = za ? 0.f : vd;
        uint64_t zam = rfl64(__ballot(za));

        acc = (icur_s - 0.2f * icur_s) + Sain + accP.x;
        {
            uint64_t m = (em >> 48);                    // variable action bits (few)
            while (m) { int k = __builtin_ctzll(m); m &= m - 1; acc += wain32[(k << 6) + lane]; }
        }
        float icur_a = acc;

        // ---- layer c ----
        vd = va_new + 0.1f * (icur_a - va_new);
        bool zc = (vd - 1.0f) > 0.f;
        v = zc ? 0.f : vd;
        zmask = rfl64(__ballot(zc));

        acc = (icur_a - 0.2f * icur_a) + accP.y;
        {
            float a0 = 0.f, a1 = 0.f;
            uint64_t m = zam;                           // fold = Wcin2 + Wcrec, f32 LDS
            while (m) {
                int k = __builtin_ctzll(m); m &= m - 1; a0 += lds[4096 + (k << 6) + lane];
                if (m) { k = __builtin_ctzll(m); m &= m - 1; a1 += lds[4096 + (k << 6) + lane]; }
            }
            acc += a0 + a1;
        }
        icur = acc;

        // ---- LI readout (feed-forward only -> f32 reduce) ----
        float p = zc ? wro : 0.f;
        #pragma unroll
        for (int off = 32; off >= 1; off >>= 1) p += __shfl_xor(p, off, 64);
        float vnew = vli + 0.1f * (ili - vli);
        ili = (ili - 0.2f * ili) + p;
        vli = vnew;
        vmax = fmaxf(vmax, vli);
    }

    if (lane == 0) out[row] = vmax;
}

extern "C" void kernel_launch(void* const* d_in, const int* in_sizes, int n_in,
                              void* d_out, int out_size, void* d_ws, size_t ws_size,
                              hipStream_t stream) {
    const float* state  = (const float*)d_in[0];
    const float* action = (const float*)d_in[1];
    const float* Wsin   = (const float*)d_in[2];
    const float* Wsrec  = (const float*)d_in[3];
    const float* Wain   = (const float*)d_in[4];
    const float* Warec  = (const float*)d_in[5];
    const float* Wcin   = (const float*)d_in[6];
    const float* Wcrec  = (const float*)d_in[7];
    const float* Wro    = (const float*)d_in[8];
    float* out = (float*)d_out;
    float* ws  = (float*)d_ws;

    const int B = in_sizes[0] / 24;  // 16384
    snn_prep<<<46, 256, 0, stream>>>(Wsin, Wain, Warec, Wcin, ws);
    snn_main<<<B / 16, 1024, 0, stream>>>(state, action, Wsrec, Wcin, Wcrec, Wro, ws, out);
}